// Round 1
// baseline (14009.657 us; speedup 1.0000x reference)
//
#include <hip/hip_runtime.h>

// ---------------------------------------------------------------------------
// Equilibrium-prop fixed-point net, MI355X.
// Key identities: d_rho(u) == 1 always (u in [0,1] by construction), so
//   u1' = clip(0.5*(u1 + xW0 + u2@W1^T))
//   u2' = clip(0.5*(u2 + u1@W1 + u3@W2^T + b1))
//   u3' = clip(0.5*(u3 + u2@W2 + u4@W3^T + b2))
//   u4' = clip(0.5*(u4 + u3@W3 + b3))              (free)
//   u4' = clip(0.5*(u3@W3 + b3 + t))               (clamped, u4 cancels)
// Precision: split-bf16 (hi+lo) MFMA, 3 terms (hh, hl, lh), fp32 accum.
// One cooperative kernel; 8 sample-clusters of 32 samples, per-cluster
// epoch barrier (agent-scope atomics).
// ---------------------------------------------------------------------------

typedef float  f32x4 __attribute__((ext_vector_type(4)));
typedef short  s16x8 __attribute__((ext_vector_type(8)));

#define MFMA_BF16 __builtin_amdgcn_mfma_f32_16x16x32_bf16

#define NFREE   500
#define NCLAMP  8
#define NITER   (NFREE + NCLAMP)
#define ROWLEN  1568                   // [u1:512 | u2:512 | u3:512 | u4:32]
#define NSAMP   256
#define ROWTOT  (NSAMP * ROWLEN)

// packed-B element offsets (each block = 512 elems = one (ctile,kstep) frag set)
#define B1_OFF   0                     // W1^T   (u1' <- u2), 32ct x 16ks
#define B2A_OFF  262144                // W1     (u2' <- u1)
#define B2B_OFF  524288                // W2^T   (u2' <- u3)
#define B3A_OFF  786432                // W2     (u3' <- u2)
#define B3B_OFF  1048576               // W3^T   (u3' <- u4), 32ct x 1ks
#define B4_OFF   1064960               // W3 (unused by MFMA path; u4 via VALU)
#define BTOT     1081344

// workspace layout (bytes); all section sizes 16B-aligned
#define WS_U32   0                                   // fp32 state, 2 bufs
#define WS_UH    (WS_U32 + 2*ROWTOT*4)               // bf16 hi, 2 bufs
#define WS_UL    (WS_UH  + 2*ROWTOT*2)               // bf16 lo, 2 bufs
#define WS_XW0   (WS_UL  + 2*ROWTOT*2)               // x@W0+b0, [256][512] f32
#define WS_BIAS  (WS_XW0 + NSAMP*512*4)              // [1568] f32
#define WS_CNT   (WS_BIAS + 6400)                    // 8 padded barrier ctrs
#define WS_BH    (WS_CNT + 512)
#define WS_BL    (WS_BH + BTOT*2)
#define WS_END   (WS_BL + BTOT*2)                    // ~11.3 MB

__device__ __forceinline__ short f2bf(float f){      // RNE f32->bf16
  unsigned u = __float_as_uint(f);
  unsigned r = (u + 0x7FFFu + ((u >> 16) & 1u)) >> 16;
  return (short)r;
}
__device__ __forceinline__ float bf2f(short s){
  return __uint_as_float(((unsigned)(unsigned short)s) << 16);
}

// -------------------------- init: state, bias, counters ---------------------
__global__ void initK(const float* __restrict__ u1, const float* __restrict__ u2,
                      const float* __restrict__ u3, const float* __restrict__ u4,
                      const float* __restrict__ b1, const float* __restrict__ b2,
                      float* __restrict__ u32b, short* __restrict__ uhb,
                      short* __restrict__ ulb, float* __restrict__ bias,
                      unsigned* __restrict__ cnt){
  const int b = blockIdx.x, tid = threadIdx.x;
  for (int col = tid; col < ROWLEN; col += 256){
    float v;
    if      (col < 512)  v = (col < 500)        ? u1[b*500 + col]        : 0.f;
    else if (col < 1024) v = ((col-512) < 500)  ? u2[b*500 + col - 512]  : 0.f;
    else if (col < 1536) v = ((col-1024) < 500) ? u3[b*500 + col - 1024] : 0.f;
    else                 v = ((col-1536) < 10)  ? u4[b*10 + col - 1536]  : 0.f;
    const int idx = b*ROWLEN + col;
    u32b[idx] = v;
    short h = f2bf(v); uhb[idx] = h; ulb[idx] = f2bf(v - bf2f(h));
    if (b == 0){
      float bv = 0.f;
      if      (col >= 512  && col < 1024){ int i = col-512;  if (i < 500) bv = b1[i]; }
      else if (col >= 1024 && col < 1536){ int i = col-1024; if (i < 500) bv = b2[i]; }
      bias[col] = bv;                  // u1 segment bias lives in xW0p
    }
  }
  if (b == 0 && tid < 128) cnt[tid] = 0;
}

// -------------------------- xW0p = x @ W0 + b0 (fp32) -----------------------
__global__ void xw0K(const float* __restrict__ x, const float* __restrict__ W0,
                     const float* __restrict__ b0, float* __restrict__ xw0p){
  __shared__ float xs[784];
  const int b = blockIdx.x, tid = threadIdx.x;    // 512 threads
  for (int j = tid; j < 784; j += 512) xs[j] = x[b*784 + j];
  __syncthreads();
  float a = 0.f;
  if (tid < 500){
    a = b0[tid];
    #pragma unroll 4
    for (int j = 0; j < 784; ++j) a = fmaf(xs[j], W0[j*500 + tid], a);
  }
  xw0p[b*512 + tid] = (tid < 500) ? a : 0.f;
}

// ------------------- pack weights into MFMA B-fragment layout ---------------
// frag element (lane, j): k = ks*32 + (lane>>4)*8 + j ; c = ct*16 + (lane&15)
__global__ void packK(const float* __restrict__ W1, const float* __restrict__ W2,
                      const float* __restrict__ W3, short* __restrict__ Bh,
                      short* __restrict__ Bl){
  const int bid = blockIdx.x, ln = threadIdx.x;   // 64 threads
  int m, base, nks, poff;
  if      (bid < 512) { m=0; base=0;    nks=16; poff=B1_OFF;  }
  else if (bid < 1024){ m=1; base=512;  nks=16; poff=B2A_OFF; }
  else if (bid < 1536){ m=2; base=1024; nks=16; poff=B2B_OFF; }
  else if (bid < 2048){ m=3; base=1536; nks=16; poff=B3A_OFF; }
  else if (bid < 2080){ m=4; base=2048; nks=1;  poff=B3B_OFF; }
  else                { m=5; base=2080; nks=16; poff=B4_OFF;  }
  const int local = bid - base, ct = local / nks, ks = local % nks;
  short hv[8], lv[8];
  #pragma unroll
  for (int j = 0; j < 8; ++j){
    const int k = ks*32 + (ln>>4)*8 + j;
    const int c = ct*16 + (ln & 15);
    float v = 0.f;
    if      (m==0){ if (k<500 && c<500) v = W1[c*500 + k]; }   // W1^T
    else if (m==1){ if (k<500 && c<500) v = W1[k*500 + c]; }   // W1
    else if (m==2){ if (k<500 && c<500) v = W2[c*500 + k]; }   // W2^T
    else if (m==3){ if (k<500 && c<500) v = W2[k*500 + c]; }   // W2
    else if (m==4){ if (k<10  && c<500) v = W3[c*10  + k]; }   // W3^T
    else          { if (k<500 && c<10 ) v = W3[k*10  + c]; }   // W3
    short h = f2bf(v); hv[j] = h; lv[j] = f2bf(v - bf2f(h));
  }
  const int o = poff + (ct*nks + ks)*512 + ln*8;
  #pragma unroll
  for (int j = 0; j < 8; ++j){ Bh[o+j] = hv[j]; Bl[o+j] = lv[j]; }
}

// ------------------------------- main loop ----------------------------------
// grid 256 WGs x 256 thr. cluster=bid&7 (32 samples), rank=bid>>3.
// ranks 0..15: u2 tiles (K=1024, 32 ksteps). ranks 16..31: fused u1+u3
// (shared A=u2 reads, 16 ksteps x 2 outputs + 1 u4-seg tail).
// wave wv: s=wv>>1 (16-sample tile), ci=wv&1 (16-col tile of the 32-col pair).
__global__ void __launch_bounds__(256, 2) mainK(
    const short* __restrict__ Bh, const short* __restrict__ Bl,
    float* __restrict__ u32b, short* __restrict__ uhb, short* __restrict__ ulb,
    const float* __restrict__ xw0p, const float* __restrict__ bias,
    const float* __restrict__ tin, const float* __restrict__ b3,
    const float* __restrict__ W3, float* __restrict__ dout,
    unsigned* __restrict__ cnt)
{
  __shared__ float red[256];
  const int bid = blockIdx.x;
  const int cl  = bid & 7;
  const int rk  = bid >> 3;
  const int tid = threadIdx.x;
  const int wv  = tid >> 6;
  const int ln  = tid & 63;
  const int s   = wv >> 1;
  const int ci  = wv & 1;
  const int sbase = cl * 32;
  const int lrow  = ln & 15;
  const int lkg   = ln >> 4;
  const int rowA  = sbase + s*16 + lrow;
  const int aBase = rowA*ROWLEN + lkg*8;
  const int b4    = sbase + rk;            // this WG's u4 sample

  for (int it = 0; it < NITER; ++it){
    const int buf = it & 1, nbuf = buf ^ 1;
    const short* uhB = uhb + (size_t)buf*ROWTOT;
    const short* ulB = ulb + (size_t)buf*ROWTOT;
    const float* uoB = u32b + (size_t)buf*ROWTOT;
    float* uoN = u32b + (size_t)nbuf*ROWTOT;
    short* uhN = uhb + (size_t)nbuf*ROWTOT;
    short* ulN = ulb + (size_t)nbuf*ROWTOT;
    const int snap = (it == NFREE-1) ? 0 : ((it == NITER-1) ? 386560 : -1);
    const bool clamped = (it >= NFREE);

    f32x4 acc0 = {0.f,0.f,0.f,0.f};
    f32x4 acc1 = {0.f,0.f,0.f,0.f};

    if (rk < 16){
      const int ctL = rk*2 + ci;
      #pragma unroll 4
      for (int k = 0; k < 32; ++k){
        const int seg = k >> 4, ksl = k & 15;
        const int ao  = aBase + (seg << 10) + ksl*32;         // A: u1 then u3
        const int bo  = (seg ? B2B_OFF : B2A_OFF) + (ctL*16 + ksl)*512 + ln*8;
        s16x8 aH = *(const s16x8*)(uhB + ao);
        s16x8 aL = *(const s16x8*)(ulB + ao);
        s16x8 bH = *(const s16x8*)(Bh + bo);
        s16x8 bL = *(const s16x8*)(Bl + bo);
        acc0 = MFMA_BF16(aH, bH, acc0, 0, 0, 0);
        acc0 = MFMA_BF16(aH, bL, acc0, 0, 0, 0);
        acc0 = MFMA_BF16(aL, bH, acc0, 0, 0, 0);
      }
    } else {
      const int ctL = (rk-16)*2 + ci;
      #pragma unroll 2
      for (int k = 0; k < 16; ++k){
        const int ao  = aBase + 512 + k*32;                   // A: u2 (shared)
        s16x8 aH = *(const s16x8*)(uhB + ao);
        s16x8 aL = *(const s16x8*)(ulB + ao);
        const int bo1 = B1_OFF  + (ctL*16 + k)*512 + ln*8;    // -> u1'
        const int bo3 = B3A_OFF + (ctL*16 + k)*512 + ln*8;    // -> u3'
        s16x8 bH1 = *(const s16x8*)(Bh + bo1);
        s16x8 bL1 = *(const s16x8*)(Bl + bo1);
        s16x8 bH3 = *(const s16x8*)(Bh + bo3);
        s16x8 bL3 = *(const s16x8*)(Bl + bo3);
        acc0 = MFMA_BF16(aH, bH1, acc0, 0, 0, 0);
        acc0 = MFMA_BF16(aH, bL1, acc0, 0, 0, 0);
        acc0 = MFMA_BF16(aL, bH1, acc0, 0, 0, 0);
        acc1 = MFMA_BF16(aH, bH3, acc1, 0, 0, 0);
        acc1 = MFMA_BF16(aH, bL3, acc1, 0, 0, 0);
        acc1 = MFMA_BF16(aL, bH3, acc1, 0, 0, 0);
      }
      { // u3' tail: A = u4 segment [1536,1568), B = W3^T
        const int ao = aBase + 1536;
        s16x8 aH = *(const s16x8*)(uhB + ao);
        s16x8 aL = *(const s16x8*)(ulB + ao);
        const int bo = B3B_OFF + ctL*512 + ln*8;
        s16x8 bH = *(const s16x8*)(Bh + bo);
        s16x8 bL = *(const s16x8*)(Bl + bo);
        acc1 = MFMA_BF16(aH, bH, acc1, 0, 0, 0);
        acc1 = MFMA_BF16(aH, bL, acc1, 0, 0, 0);
        acc1 = MFMA_BF16(aL, bH, acc1, 0, 0, 0);
      }
    }

    // ---- epilogue: u' = clip(0.5*(u_old + acc + bias [+ xW0])) ----
    // C/D layout (m89-verified): row = (ln>>4)*4 + r, col = ln&15
    auto writeTile = [&](f32x4 acc, int cg0){
      #pragma unroll
      for (int r = 0; r < 4; ++r){
        const int b   = sbase + s*16 + lkg*4 + r;
        const int col = cg0 + lrow;
        float y = acc[r] + bias[col];
        if (col < 512) y += xw0p[b*512 + col];
        const float uold = uoB[b*ROWLEN + col];
        float v = 0.5f*(uold + y);
        v = fminf(fmaxf(v, 0.f), 1.f);
        const int i = col & 511;
        if (i >= 500) v = 0.f;                         // keep K-pads zero
        const int idx = b*ROWLEN + col;
        uoN[idx] = v;
        short h = f2bf(v); uhN[idx] = h; ulN[idx] = f2bf(v - bf2f(h));
        if (snap >= 0 && i < 500)
          dout[snap + (col>>9)*128000 + b*500 + i] = v;
      }
    };
    if (rk < 16){
      writeTile(acc0, 512 + rk*32 + ci*16);
    } else {
      writeTile(acc0, (rk-16)*32 + ci*16);
      writeTile(acc1, 1024 + (rk-16)*32 + ci*16);
    }

    // ---- u4 update in fp32 VALU: one sample per WG ----
    {
      const int c = tid & 15, jb = tid >> 4;
      float p = 0.f;
      if (c < 10){
        #pragma unroll 4
        for (int jj = 0; jj < 32; ++jj){
          const int j = jb*32 + jj;
          if (j < 500) p = fmaf(uoB[b4*ROWLEN + 1024 + j], W3[j*10 + c], p);
        }
      }
      red[tid] = p;
      __syncthreads();
      if (tid < 32){
        float v = 0.f;
        if (tid < 10){
          float sum = 0.f;
          #pragma unroll
          for (int q = 0; q < 16; ++q) sum += red[q*16 + tid];
          const float y4 = sum + b3[tid];
          v = clamped ? 0.5f*(y4 + tin[b4*10 + tid])
                      : 0.5f*(uoB[b4*ROWLEN + 1536 + tid] + y4);
          v = fminf(fmaxf(v, 0.f), 1.f);
        }
        const int idx = b4*ROWLEN + 1536 + tid;        // cols 1536..1567 incl pads
        uoN[idx] = v;
        short h = f2bf(v); uhN[idx] = h; ulN[idx] = f2bf(v - bf2f(h));
        if (snap >= 0 && tid < 10) dout[snap + 384000 + b4*10 + tid] = v;
      }
    }

    // ---- per-cluster epoch barrier (agent scope, monotone counter) ----
    __syncthreads();
    if (tid == 0){
      __threadfence();                                 // agent release of data
      __hip_atomic_fetch_add(&cnt[cl*16], 1u, __ATOMIC_RELEASE,
                             __HIP_MEMORY_SCOPE_AGENT);
      const unsigned target = 32u * (unsigned)(it + 1);
      int pc = 0;
      while (__hip_atomic_load(&cnt[cl*16], __ATOMIC_RELAXED,
                               __HIP_MEMORY_SCOPE_AGENT) < target){
        __builtin_amdgcn_s_sleep(1);
        if (((++pc) & 63) == 0)
          (void)__hip_atomic_load(&cnt[cl*16], __ATOMIC_ACQUIRE,
                                  __HIP_MEMORY_SCOPE_AGENT);
      }
      (void)__hip_atomic_load(&cnt[cl*16], __ATOMIC_ACQUIRE,
                              __HIP_MEMORY_SCOPE_AGENT);
    }
    __syncthreads();
  }
}

// ------------------------------- launcher -----------------------------------
extern "C" void kernel_launch(void* const* d_in, const int* in_sizes, int n_in,
                              void* d_out, int out_size, void* d_ws, size_t ws_size,
                              hipStream_t stream)
{
  const float* x  = (const float*)d_in[0];
  const float* u1 = (const float*)d_in[1];
  const float* u2 = (const float*)d_in[2];
  const float* u3 = (const float*)d_in[3];
  const float* u4 = (const float*)d_in[4];
  const float* t  = (const float*)d_in[5];
  const float* W0 = (const float*)d_in[6];
  const float* W1 = (const float*)d_in[7];
  const float* W2 = (const float*)d_in[8];
  const float* W3 = (const float*)d_in[9];
  const float* b0 = (const float*)d_in[10];
  const float* b1 = (const float*)d_in[11];
  const float* b2 = (const float*)d_in[12];
  const float* b3 = (const float*)d_in[13];

  char* ws = (char*)d_ws;
  float*    u32b = (float*)   (ws + WS_U32);
  short*    uhb  = (short*)   (ws + WS_UH);
  short*    ulb  = (short*)   (ws + WS_UL);
  float*    xw0p = (float*)   (ws + WS_XW0);
  float*    bias = (float*)   (ws + WS_BIAS);
  unsigned* cnt  = (unsigned*)(ws + WS_CNT);
  short*    Bh   = (short*)   (ws + WS_BH);
  short*    Bl   = (short*)   (ws + WS_BL);
  float*    dout = (float*)d_out;

  initK<<<256, 256, 0, stream>>>(u1, u2, u3, u4, b1, b2, u32b, uhb, ulb, bias, cnt);
  xw0K<<<256, 512, 0, stream>>>(x, W0, b0, xw0p);
  packK<<<2112, 64, 0, stream>>>(W1, W2, W3, Bh, Bl);

  void* args[] = { &Bh, &Bl, &u32b, &uhb, &ulb, &xw0p, &bias,
                   &t, &b3, &W3, &dout, &cnt };
  hipError_t e = hipLaunchCooperativeKernel((const void*)mainK, dim3(256),
                                            dim3(256), args, 0, stream);
  if (e != hipSuccess){
    // fallback: plain launch (256 small WGs on 256 CUs are co-resident in
    // practice; barrier semantics unchanged)
    mainK<<<256, 256, 0, stream>>>(Bh, Bl, u32b, uhb, ulb, xw0p, bias,
                                   t, b3, W3, dout, cnt);
  }
  (void)in_sizes; (void)n_in; (void)out_size; (void)ws_size;
}

// Round 2
// 3987.181 us; speedup vs baseline: 3.5137x; 3.5137x over previous
//
#include <hip/hip_runtime.h>

// ---------------------------------------------------------------------------
// Equilibrium-prop fixed-point net, MI355X — R2.
//   u1' = clip(0.5*(u1 + xW0 + u2@W1^T))
//   u2' = clip(0.5*(u2 + u1@W1 + u3@W2^T + b1))
//   u3' = clip(0.5*(u3 + u2@W2 + u4@W3^T + b2))
//   u4' = clip(0.5*(u4 + u3@W3 + b3))   (free) | clip(0.5*(u3@W3+b3+t)) (clamped)
// R2 design:
//  - B-weights packed to MFMA frags once, then REGISTER-CACHED per wave
//    (256 VGPRs) across all 508 iterations; weights stay L2-resident.
//  - state = one u32/elem (bf16 hi | lo<<16), double-buffered in ws; ALL
//    cross-WG accesses use sc0 sc1 (system-coherent at LLC) -> NO cache
//    fences anywhere, L2 never invalidated.
//  - fp32 master state lives in the owning lane's registers (fixed tiling).
//  - per-iter: each WG bulk-stages its 16-row A-panel (hi/lo split) into
//    swizzled LDS (2-way-conflict-free ds_read_b128), then K-loop of MFMAs.
//  - 16 independent row-groups (16 samples); barrier = 16 WGs via relaxed
//    system-scope counter + s_waitcnt vmcnt(0). No threadfence.
// ---------------------------------------------------------------------------

typedef float  f32x4 __attribute__((ext_vector_type(4)));
typedef short  s16x8 __attribute__((ext_vector_type(8)));
typedef short  s16x4 __attribute__((ext_vector_type(4)));
typedef unsigned int uint;
typedef uint   u32x4 __attribute__((ext_vector_type(4)));

#define MFMA_BF16 __builtin_amdgcn_mfma_f32_16x16x32_bf16

#define NFREE   500
#define NCLAMP  8
#define NITER   (NFREE + NCLAMP)
#define ROWLEN  1568                   // [u1:512 | u2:512 | u3:512 | u4:32]
#define NSAMP   256
#define ROWTOT  (NSAMP * ROWLEN)

// packed-B element offsets (each block = 512 elems = one (ctile,kstep) frag)
#define B1_OFF   0                     // W1^T   (u1' <- u2), 32ct x 16ks
#define B2A_OFF  262144                // W1     (u2' <- u1)
#define B2B_OFF  524288                // W2^T   (u2' <- u3)
#define B3A_OFF  786432                // W2     (u3' <- u2)
#define B3B_OFF  1048576               // W3^T   (u3' <- u4), 32ct x 1ks
#define B4_OFF   1064960               // W3     (u4' <- u3), 1ct(+pad) x 16ks
#define BTOT     1081344

// workspace layout (bytes)
#define WS_UHL   0                                   // 2 bufs x ROWTOT u32
#define WS_XW0   (WS_UHL + 2*ROWTOT*4)               // x@W0+b0, [256][512] f32
#define WS_BIAS  (WS_XW0 + NSAMP*512*4)              // [1568] f32
#define WS_CNT   (WS_BIAS + 6400)                    // 16 padded counters
#define WS_BH    (WS_CNT + 1024)
#define WS_BL    (WS_BH + BTOT*2)
#define WS_END   (WS_BL + BTOT*2)                    // ~8.07 MB

__device__ __forceinline__ short f2bf(float f){      // RNE f32->bf16
  unsigned u = __float_as_uint(f);
  unsigned r = (u + 0x7FFFu + ((u >> 16) & 1u)) >> 16;
  return (short)r;
}
__device__ __forceinline__ float bf2f(short s){
  return __uint_as_float(((unsigned)(unsigned short)s) << 16);
}
__device__ __forceinline__ uint packbf(float v){
  short h = f2bf(v);
  short l = f2bf(v - bf2f(h));
  return (uint)(unsigned short)h | ((uint)(unsigned short)l << 16);
}

// system-scope (LLC-coherent, L2-bypassing) accesses — no cache fences needed
#define SYSLD(dst, addr) \
  asm volatile("global_load_dwordx4 %0, %1, off sc0 sc1" : "=v"(dst) : "v"(addr) : "memory")
__device__ __forceinline__ void store_sys(uint* p, uint v){
  asm volatile("global_store_dword %0, %1, off sc0 sc1" :: "v"(p), "v"(v) : "memory");
}
// counted-vmcnt wait tied to the register about to be consumed (rule #18)
#define VMW_(N, X) do { \
  asm volatile("s_waitcnt vmcnt(" #N ")\n//%0" : "+v"(X) :: "memory"); \
  __builtin_amdgcn_sched_barrier(0); } while(0)
#define VMW(N, X) VMW_(N, X)
// wait + unpack hi/lo + swizzled LDS write (hi at OFF, lo at OFF+32768)
#define PRC(N, X, OFF) do { \
  VMW(N, X); \
  s16x4 h_ = (s16x4){ (short)((X)[0] & 0xffff), (short)((X)[1] & 0xffff), \
                      (short)((X)[2] & 0xffff), (short)((X)[3] & 0xffff) }; \
  s16x4 l_ = (s16x4){ (short)((X)[0] >> 16), (short)((X)[1] >> 16), \
                      (short)((X)[2] >> 16), (short)((X)[3] >> 16) }; \
  *(s16x4*)(L + (OFF)) = h_; *(s16x4*)(L + 32768 + (OFF)) = l_; } while(0)

#define BARRIER(ITV) do { \
  asm volatile("s_waitcnt vmcnt(0)" ::: "memory"); \
  __syncthreads(); \
  if (tid == 0){ \
    __hip_atomic_fetch_add(cg, 1u, __ATOMIC_RELAXED, __HIP_MEMORY_SCOPE_SYSTEM); \
    const unsigned tgt_ = 16u * (unsigned)((ITV) + 1); \
    while (__hip_atomic_load(cg, __ATOMIC_RELAXED, __HIP_MEMORY_SCOPE_SYSTEM) < tgt_){ \
      __builtin_amdgcn_s_sleep(1); \
    } \
  } \
  __syncthreads(); } while(0)

// -------------------------- init: packed state, bias, counters --------------
__global__ void initK(const float* __restrict__ u1, const float* __restrict__ u2,
                      const float* __restrict__ u3, const float* __restrict__ u4,
                      const float* __restrict__ b1, const float* __restrict__ b2,
                      uint* __restrict__ uhl, float* __restrict__ bias,
                      uint* __restrict__ cnt){
  const int b = blockIdx.x, tid = threadIdx.x;
  for (int col = tid; col < ROWLEN; col += 256){
    float v;
    if      (col < 512)  v = (col < 500)        ? u1[b*500 + col]        : 0.f;
    else if (col < 1024) v = ((col-512) < 500)  ? u2[b*500 + col - 512]  : 0.f;
    else if (col < 1536) v = ((col-1024) < 500) ? u3[b*500 + col - 1024] : 0.f;
    else                 v = ((col-1536) < 10)  ? u4[b*10 + col - 1536]  : 0.f;
    uhl[b*ROWLEN + col] = packbf(v);
    if (b == 0){
      float bv = 0.f;
      if      (col >= 512  && col < 1024){ int i = col-512;  if (i < 500) bv = b1[i]; }
      else if (col >= 1024 && col < 1536){ int i = col-1024; if (i < 500) bv = b2[i]; }
      bias[col] = bv;
    }
  }
  if (b == 0) cnt[tid] = 0;
}

// -------------------------- xW0p = x @ W0 + b0 (fp32) -----------------------
__global__ void xw0K(const float* __restrict__ x, const float* __restrict__ W0,
                     const float* __restrict__ b0, float* __restrict__ xw0p){
  __shared__ float xs[784];
  const int b = blockIdx.x, tid = threadIdx.x;    // 512 threads
  for (int j = tid; j < 784; j += 512) xs[j] = x[b*784 + j];
  __syncthreads();
  float a = 0.f;
  if (tid < 500){
    a = b0[tid];
    #pragma unroll 4
    for (int j = 0; j < 784; ++j) a = fmaf(xs[j], W0[j*500 + tid], a);
  }
  xw0p[b*512 + tid] = (tid < 500) ? a : 0.f;
}

// ------------------- pack weights into MFMA B-fragment layout ---------------
__global__ void packK(const float* __restrict__ W1, const float* __restrict__ W2,
                      const float* __restrict__ W3, short* __restrict__ Bh,
                      short* __restrict__ Bl){
  const int bid = blockIdx.x, ln = threadIdx.x;   // 64 threads
  int m, base, nks, poff;
  if      (bid < 512) { m=0; base=0;    nks=16; poff=B1_OFF;  }
  else if (bid < 1024){ m=1; base=512;  nks=16; poff=B2A_OFF; }
  else if (bid < 1536){ m=2; base=1024; nks=16; poff=B2B_OFF; }
  else if (bid < 2048){ m=3; base=1536; nks=16; poff=B3A_OFF; }
  else if (bid < 2080){ m=4; base=2048; nks=1;  poff=B3B_OFF; }
  else                { m=5; base=2080; nks=16; poff=B4_OFF;  }
  const int local = bid - base, ct = local / nks, ks = local % nks;
  short hv[8], lv[8];
  #pragma unroll
  for (int j = 0; j < 8; ++j){
    const int k = ks*32 + (ln>>4)*8 + j;
    const int c = ct*16 + (ln & 15);
    float v = 0.f;
    if      (m==0){ if (k<500 && c<500) v = W1[c*500 + k]; }   // W1^T
    else if (m==1){ if (k<500 && c<500) v = W1[k*500 + c]; }   // W1
    else if (m==2){ if (k<500 && c<500) v = W2[c*500 + k]; }   // W2^T
    else if (m==3){ if (k<500 && c<500) v = W2[k*500 + c]; }   // W2
    else if (m==4){ if (k<10  && c<500) v = W3[c*10  + k]; }   // W3^T
    else          { if (k<500 && c<10 ) v = W3[k*10  + c]; }   // W3
    short h = f2bf(v); hv[j] = h; lv[j] = f2bf(v - bf2f(h));
  }
  const int o = poff + (ct*nks + ks)*512 + ln*8;
  #pragma unroll
  for (int j = 0; j < 8; ++j){ Bh[o+j] = hv[j]; Bl[o+j] = lv[j]; }
}

// ------------------------------- main loop ----------------------------------
// 256 WGs x 256 thr, 1 WG/CU. rg = bid&15 (16 samples), tp = bid>>4:
//   tp 0-7 : u2' WG, 64 cols (cb=tp), K=1024 (u1 then u3), 1 ct/wave
//   tp 8-11: u1' WG, 128 cols, K=512 (u2), 2 ct/wave
//   tp12-15: u3' WG, 128 cols, K=512+32 (u2 then u4), 2 ct/wave
// u4'-tile: tp==0, wave 0 (A=u3 from LDS, B4 streamed from L2).
__global__ void __launch_bounds__(256, 1) mainK(
    const short* __restrict__ Bh, const short* __restrict__ Bl,
    uint* __restrict__ uhl, const float* __restrict__ xw0p,
    const float* __restrict__ bias,
    const float* __restrict__ u1in, const float* __restrict__ u2in,
    const float* __restrict__ u3in, const float* __restrict__ u4in,
    const float* __restrict__ tin, const float* __restrict__ b3,
    float* __restrict__ dout, uint* __restrict__ cnt)
{
  __shared__ short ldss[32768];                 // 64 KiB: hi [0,32K), lo [32K,64K)
  char* L = (char*)ldss;
  const int bid = blockIdx.x;
  const int rg  = bid & 15;
  const int tp  = bid >> 4;
  const int tid = threadIdx.x;
  const int wv  = tid >> 6, ln = tid & 63;
  const int lrow = ln & 15, lkg = ln >> 4;
  const int rowbase = rg * 16;
  const int sg16 = tid >> 4, l16 = tid & 15;
  // A-frag LDS base: row*2048 + (k-group*16 ^ swizzle); ks*64 XORs in later
  const int abase = lrow*2048 + ((lkg*16) ^ ((lrow & 7) << 4));
  uint* cg = cnt + rg*16;

  if (tp < 8){
    // =============================== u2 path ===============================
    s16x8 bh[32], bl[32];                       // 256 VGPRs, live whole kernel
    const int ctg = tp*4 + wv;
    #pragma unroll
    for (int ks = 0; ks < 32; ++ks){
      const int of = (ks < 16 ? B2A_OFF + (ctg*16 + ks)*512
                              : B2B_OFF + (ctg*16 + ks - 16)*512) + ln*8;
      bh[ks] = *(const s16x8*)(Bh + of);
      bl[ks] = *(const s16x8*)(Bl + of);
    }
    const int i0 = tp*64 + wv*16 + lrow;        // col within u2 segment
    const int colg = 512 + i0;
    const float biasv = bias[colg];
    f32x4 uold, uold4;
    #pragma unroll
    for (int r = 0; r < 4; ++r){
      const int b = rowbase + lkg*4 + r;
      uold[r]  = (i0 < 500)   ? u2in[b*500 + i0]  : 0.f;
      uold4[r] = (lrow < 10)  ? u4in[b*10 + lrow] : 0.f;
    }
    const int rA = sg16 >> 1, half = sg16 & 1;
    const bool doU4 = (tp == 0 && wv == 0);

    for (int it = 0; it < NITER; ++it){
      const uint* uhlB = uhl + (size_t)(it & 1)*ROWTOT;
      uint*       uhlN = uhl + (size_t)((it & 1) ^ 1)*ROWTOT;
      const int snap = (it == NFREE-1) ? 0 : ((it == NITER-1) ? 386560 : -1);
      { // ---- stage A = u1 (half0) + u3 (half1), rows rA and rA+8 ----
        const uint* sA = uhlB + (size_t)(rowbase + rA)*ROWLEN + half*1024 + l16*4;
        const uint* sB = sA + 8*ROWLEN;
        u32x4 a0,a1,a2,a3,a4,a5,a6,a7,c0,c1,c2,c3,c4,c5,c6,c7;
        SYSLD(a0, sA+0);   SYSLD(a1, sA+64);  SYSLD(a2, sA+128); SYSLD(a3, sA+192);
        SYSLD(a4, sA+256); SYSLD(a5, sA+320); SYSLD(a6, sA+384); SYSLD(a7, sA+448);
        SYSLD(c0, sB+0);   SYSLD(c1, sB+64);  SYSLD(c2, sB+128); SYSLD(c3, sB+192);
        SYSLD(c4, sB+256); SYSLD(c5, sB+320); SYSLD(c6, sB+384); SYSLD(c7, sB+448);
        const int obA = rA*2048 + ((half*1024 + l16*8) ^ ((rA & 7) << 4));
        const int obB = obA + 16384;            // row+8: same swizzle bits
        PRC(15, a0, obA+0);   PRC(14, a1, obA+128); PRC(13, a2, obA+256); PRC(12, a3, obA+384);
        PRC(11, a4, obA+512); PRC(10, a5, obA+640); PRC(9,  a6, obA+768); PRC(8,  a7, obA+896);
        PRC(7,  c0, obB+0);   PRC(6,  c1, obB+128); PRC(5,  c2, obB+256); PRC(4,  c3, obB+384);
        PRC(3,  c4, obB+512); PRC(2,  c5, obB+640); PRC(1,  c6, obB+768); PRC(0,  c7, obB+896);
      }
      __syncthreads();
      f32x4 acc = {0.f,0.f,0.f,0.f};
      #pragma unroll
      for (int ks = 0; ks < 32; ++ks){
        const int off = abase ^ (ks*64);
        s16x8 aH = *(const s16x8*)(L + off);
        s16x8 aL = *(const s16x8*)(L + 32768 + off);
        acc = MFMA_BF16(aH, bh[ks], acc, 0, 0, 0);
        acc = MFMA_BF16(aH, bl[ks], acc, 0, 0, 0);
        acc = MFMA_BF16(aL, bh[ks], acc, 0, 0, 0);
      }
      f32x4 acc4 = {0.f,0.f,0.f,0.f};
      if (doU4){
        #pragma unroll
        for (int ks = 0; ks < 16; ++ks){
          const int off = (abase + 1024) ^ (ks*64);   // u3 half of panel
          s16x8 aH = *(const s16x8*)(L + off);
          s16x8 aL = *(const s16x8*)(L + 32768 + off);
          const int of4 = B4_OFF + ks*512 + ln*8;
          s16x8 b4h = *(const s16x8*)(Bh + of4);
          s16x8 b4l = *(const s16x8*)(Bl + of4);
          acc4 = MFMA_BF16(aH, b4h, acc4, 0, 0, 0);
          acc4 = MFMA_BF16(aH, b4l, acc4, 0, 0, 0);
          acc4 = MFMA_BF16(aL, b4h, acc4, 0, 0, 0);
        }
      }
      // ---- epilogue: u2' ----
      #pragma unroll
      for (int r = 0; r < 4; ++r){
        const int b = rowbase + lkg*4 + r;
        const float y = acc[r] + biasv;
        float v = 0.5f*(uold[r] + y);
        v = fminf(fmaxf(v, 0.f), 1.f);
        if (i0 >= 500) v = 0.f;
        uold[r] = v;
        store_sys(uhlN + (size_t)b*ROWLEN + colg, packbf(v));
        if (snap >= 0 && i0 < 500) dout[snap + 128000 + b*500 + i0] = v;
      }
      if (doU4){
        const bool clamped = (it >= NFREE);
        #pragma unroll
        for (int r = 0; r < 4; ++r){
          const int b = rowbase + lkg*4 + r;
          float v = 0.f;
          if (lrow < 10){
            const float y = acc4[r] + b3[lrow];
            v = clamped ? 0.5f*(y + tin[b*10 + lrow]) : 0.5f*(uold4[r] + y);
            v = fminf(fmaxf(v, 0.f), 1.f);
          }
          uold4[r] = v;
          store_sys(uhlN + (size_t)b*ROWLEN + 1536 + lrow, packbf(v));
          store_sys(uhlN + (size_t)b*ROWLEN + 1552 + lrow, 0u);   // keep pads 0
          if (snap >= 0 && lrow < 10) dout[snap + 384000 + b*10 + lrow] = v;
        }
      }
      BARRIER(it);
    }
  } else {
    // ============================ u1 / u3 path =============================
    const bool IS3 = (tp >= 12);
    const int cbb  = IS3 ? (tp - 12) : (tp - 8);
    const int ct0  = cbb*8 + wv*2;
    s16x8 bh0[16], bl0[16], bh1[16], bl1[16];   // 256 VGPRs
    {
      const int base = IS3 ? B3A_OFF : B1_OFF;
      #pragma unroll
      for (int ks = 0; ks < 16; ++ks){
        const int ofA = base + ((ct0+0)*16 + ks)*512 + ln*8;
        const int ofB = base + ((ct0+1)*16 + ks)*512 + ln*8;
        bh0[ks] = *(const s16x8*)(Bh + ofA); bl0[ks] = *(const s16x8*)(Bl + ofA);
        bh1[ks] = *(const s16x8*)(Bh + ofB); bl1[ks] = *(const s16x8*)(Bl + ofB);
      }
    }
    s16x8 th0 = {0,0,0,0,0,0,0,0}, tl0 = th0, th1 = th0, tl1 = th0;  // u4 tail
    if (IS3){
      th0 = *(const s16x8*)(Bh + B3B_OFF + (ct0+0)*512 + ln*8);
      tl0 = *(const s16x8*)(Bl + B3B_OFF + (ct0+0)*512 + ln*8);
      th1 = *(const s16x8*)(Bh + B3B_OFF + (ct0+1)*512 + ln*8);
      tl1 = *(const s16x8*)(Bl + B3B_OFF + (ct0+1)*512 + ln*8);
    }
    const int colg0 = (IS3 ? 1024 : 0) + cbb*128 + wv*32;
    const int iA = (colg0 & 511) + lrow, iB = iA + 16;
    const float biasA = bias[colg0 + lrow], biasB = bias[colg0 + 16 + lrow];
    const float* uin = IS3 ? u3in : u1in;
    f32x4 uoldA, uoldB;
    #pragma unroll
    for (int r = 0; r < 4; ++r){
      const int b = rowbase + lkg*4 + r;
      uoldA[r] = (iA < 500) ? uin[b*500 + iA] : 0.f;
      uoldB[r] = (iB < 500) ? uin[b*500 + iB] : 0.f;
    }
    const int dseg = IS3 ? 256000 : 0;

    for (int it = 0; it < NITER; ++it){
      const uint* uhlB = uhl + (size_t)(it & 1)*ROWTOT;
      uint*       uhlN = uhl + (size_t)((it & 1) ^ 1)*ROWTOT;
      const int snap = (it == NFREE-1) ? 0 : ((it == NITER-1) ? 386560 : -1);
      { // ---- stage A = u2 (16 rows x 512) + u4 (16 rows x 32) ----
        const uint* sA = uhlB + (size_t)(rowbase + sg16)*ROWLEN + 512 + l16*4;
        u32x4 a0,a1,a2,a3,a4,a5,a6,a7;
        SYSLD(a0, sA+0);   SYSLD(a1, sA+64);  SYSLD(a2, sA+128); SYSLD(a3, sA+192);
        SYSLD(a4, sA+256); SYSLD(a5, sA+320); SYSLD(a6, sA+384); SYSLD(a7, sA+448);
        const int ob = sg16*2048 + ((l16*8) ^ ((sg16 & 7) << 4));
        if (tid < 128){                          // waves 0-1 also stage u4 seg
          const int row4 = tid >> 3, q = tid & 7;
          u32x4 c0;
          SYSLD(c0, uhlB + (size_t)(rowbase + row4)*ROWLEN + 1536 + q*4);
          PRC(8, a0, ob+0);   PRC(7, a1, ob+128); PRC(6, a2, ob+256); PRC(5, a3, ob+384);
          PRC(4, a4, ob+512); PRC(3, a5, ob+640); PRC(2, a6, ob+768); PRC(1, a7, ob+896);
          const int ob4 = row4*2048 + ((1024 + q*8) ^ ((row4 & 7) << 4));
          PRC(0, c0, ob4);
        } else {
          PRC(7, a0, ob+0);   PRC(6, a1, ob+128); PRC(5, a2, ob+256); PRC(4, a3, ob+384);
          PRC(3, a4, ob+512); PRC(2, a5, ob+640); PRC(1, a6, ob+768); PRC(0, a7, ob+896);
        }
      }
      __syncthreads();
      f32x4 accA = {0.f,0.f,0.f,0.f}, accB = {0.f,0.f,0.f,0.f};
      #pragma unroll
      for (int ks = 0; ks < 16; ++ks){
        const int off = abase ^ (ks*64);
        s16x8 aH = *(const s16x8*)(L + off);
        s16x8 aL = *(const s16x8*)(L + 32768 + off);
        accA = MFMA_BF16(aH, bh0[ks], accA, 0, 0, 0);
        accA = MFMA_BF16(aH, bl0[ks], accA, 0, 0, 0);
        accA = MFMA_BF16(aL, bh0[ks], accA, 0, 0, 0);
        accB = MFMA_BF16(aH, bh1[ks], accB, 0, 0, 0);
        accB = MFMA_BF16(aH, bl1[ks], accB, 0, 0, 0);
        accB = MFMA_BF16(aL, bh1[ks], accB, 0, 0, 0);
      }
      if (IS3){                                  // u4 tail kstep
        const int off = abase + 1024;
        s16x8 aH = *(const s16x8*)(L + off);
        s16x8 aL = *(const s16x8*)(L + 32768 + off);
        accA = MFMA_BF16(aH, th0, accA, 0, 0, 0);
        accA = MFMA_BF16(aH, tl0, accA, 0, 0, 0);
        accA = MFMA_BF16(aL, th0, accA, 0, 0, 0);
        accB = MFMA_BF16(aH, th1, accB, 0, 0, 0);
        accB = MFMA_BF16(aH, tl1, accB, 0, 0, 0);
        accB = MFMA_BF16(aL, th1, accB, 0, 0, 0);
      }
      // ---- epilogue: two 16x16 tiles ----
      #pragma unroll
      for (int r = 0; r < 4; ++r){
        const int b = rowbase + lkg*4 + r;
        {
          float y = accA[r] + biasA;
          if (!IS3) y += xw0p[b*512 + colg0 + lrow];
          float v = 0.5f*(uoldA[r] + y);
          v = fminf(fmaxf(v, 0.f), 1.f);
          if (iA >= 500) v = 0.f;
          uoldA[r] = v;
          store_sys(uhlN + (size_t)b*ROWLEN + colg0 + lrow, packbf(v));
          if (snap >= 0 && iA < 500) dout[snap + dseg + b*500 + iA] = v;
        }
        {
          float y = accB[r] + biasB;
          if (!IS3) y += xw0p[b*512 + colg0 + 16 + lrow];
          float v = 0.5f*(uoldB[r] + y);
          v = fminf(fmaxf(v, 0.f), 1.f);
          if (iB >= 500) v = 0.f;
          uoldB[r] = v;
          store_sys(uhlN + (size_t)b*ROWLEN + colg0 + 16 + lrow, packbf(v));
          if (snap >= 0 && iB < 500) dout[snap + dseg + b*500 + iB] = v;
        }
      }
      BARRIER(it);
    }
  }
}

// ------------------------------- launcher -----------------------------------
extern "C" void kernel_launch(void* const* d_in, const int* in_sizes, int n_in,
                              void* d_out, int out_size, void* d_ws, size_t ws_size,
                              hipStream_t stream)
{
  const float* x  = (const float*)d_in[0];
  const float* u1 = (const float*)d_in[1];
  const float* u2 = (const float*)d_in[2];
  const float* u3 = (const float*)d_in[3];
  const float* u4 = (const float*)d_in[4];
  const float* t  = (const float*)d_in[5];
  const float* W0 = (const float*)d_in[6];
  const float* W1 = (const float*)d_in[7];
  const float* W2 = (const float*)d_in[8];
  const float* W3 = (const float*)d_in[9];
  const float* b0 = (const float*)d_in[10];
  const float* b1 = (const float*)d_in[11];
  const float* b2 = (const float*)d_in[12];
  const float* b3 = (const float*)d_in[13];

  char* ws = (char*)d_ws;
  uint*  uhl  = (uint*) (ws + WS_UHL);
  float* xw0p = (float*)(ws + WS_XW0);
  float* bias = (float*)(ws + WS_BIAS);
  uint*  cnt  = (uint*) (ws + WS_CNT);
  short* Bh   = (short*)(ws + WS_BH);
  short* Bl   = (short*)(ws + WS_BL);
  float* dout = (float*)d_out;

  initK<<<256, 256, 0, stream>>>(u1, u2, u3, u4, b1, b2, uhl, bias, cnt);
  xw0K<<<256, 512, 0, stream>>>(x, W0, b0, xw0p);
  packK<<<2112, 64, 0, stream>>>(W1, W2, W3, Bh, Bl);

  void* args[] = { &Bh, &Bl, &uhl, &xw0p, &bias,
                   &u1, &u2, &u3, &u4, &t, &b3, &dout, &cnt };
  hipError_t e = hipLaunchCooperativeKernel((const void*)mainK, dim3(256),
                                            dim3(256), args, 0, stream);
  if (e != hipSuccess){
    mainK<<<256, 256, 0, stream>>>(Bh, Bl, uhl, xw0p, bias,
                                   u1, u2, u3, u4, t, b3, dout, cnt);
  }
  (void)in_sizes; (void)n_in; (void)out_size; (void)ws_size;
}